// Round 6
// baseline (118.097 us; speedup 1.0000x reference)
//
#include <hip/hip_runtime.h>
#include <stdint.h>

// ---- problem constants ----
constexpr int NB   = 4;      // batch
constexpr int CIN  = 3;
constexpr int HIN  = 256;
constexpr int COUT = 256;
constexpr int HF   = 128;              // feature H=W after stride-2 conv
constexpr int NF   = HF * HF;          // 16384
constexpr int KADM = 16;
constexpr int KK   = KADM * KADM;      // 256 descriptors
constexpr int HID  = 128;              // MLP hidden

typedef unsigned short ushort_t;
typedef __attribute__((ext_vector_type(8))) _Float16 f16x8;
typedef __attribute__((ext_vector_type(4))) float    f32x4;

__device__ inline unsigned long long shfl_xor_u64(unsigned long long v, int m) {
    unsigned lo = __shfl_xor((unsigned)v, m, 64);
    unsigned hi = __shfl_xor((unsigned)(v >> 32), m, 64);
    return ((unsigned long long)hi << 32) | lo;
}
__device__ inline unsigned long long shfl_down_u64(unsigned long long v, int off) {
    unsigned lo = __shfl_down((unsigned)v, off, 64);
    unsigned hi = __shfl_down((unsigned)(v >> 32), off, 64);
    return ((unsigned long long)hi << 32) | lo;
}
__device__ inline unsigned long long u64min(unsigned long long a, unsigned long long b) {
    return a < b ? a : b;
}
__device__ inline ushort_t f16bits(_Float16 h) { return __builtin_bit_cast(ushort_t, h); }

// =====================================================================
// Prep: split conv weights into f16 hi/lo, K padded 27->32.
// =====================================================================
__global__ __launch_bounds__(256) void prep_kernel(
        const float* __restrict__ W, ushort_t* __restrict__ Wh, ushort_t* __restrict__ Wl)
{
    int t = threadIdx.x;            // co
    #pragma unroll
    for (int q = 0; q < 32; ++q) {
        float v = (q < 27) ? W[t * 27 + q] : 0.f;
        _Float16 h = (_Float16)v;
        _Float16 l = (_Float16)(v - (float)h);
        Wh[t * 32 + q] = f16bits(h);
        Wl[t * 32 + q] = f16bits(l);
    }
}

// =====================================================================
// Conv as MFMA im2col GEMM: [64 pixels x 32(K)] x [32 x 256 channels].
// f16x2 split, 3 passes: xh*wh + xl*wh + xh*wl.
// A images: emit resp = sum_c relu(v). B images: fBT[n][c] packed h|l<<16
// (channel-contig so knn can load MFMA A-fragments directly) + normB.
// =====================================================================
__global__ __launch_bounds__(256) void conv_kernel(
        const float* __restrict__ xA, const float* __restrict__ xB,
        const ushort_t* __restrict__ Wh, const ushort_t* __restrict__ Wl,
        const float* __restrict__ bias,
        unsigned* __restrict__ fBT, float* __restrict__ resp, float* __restrict__ normB)
{
    __shared__ float    pS[CIN][3][132];    // input rows
    __shared__ ushort_t Ah[64][40];         // im2col hi, 80B row stride
    __shared__ ushort_t Al[64][40];         // im2col lo
    __shared__ float    bS[COUT];
    __shared__ float    redS[4][64];

    int blk = blockIdx.x;            // 0..2047
    int img = blk >> 8;              // 0..7
    int rem = blk & 255;
    int oh  = rem >> 1;
    int ow0 = (rem & 1) << 6;
    bool isA = (img < 4);
    int b = img & 3;
    const float* x = isA ? (xA + (size_t)b * CIN * HIN * HIN)
                         : (xB + (size_t)b * CIN * HIN * HIN);
    int tid = threadIdx.x;

    bS[tid] = bias[tid];

    for (int i = tid; i < CIN * 3 * 129; i += 256) {
        int ci = i / (3 * 129);
        int r2 = i % (3 * 129);
        int kh = r2 / 129, c = r2 % 129;
        int gr = 2 * oh - 1 + kh, gc = 2 * ow0 - 1 + c;
        float v = 0.f;
        if (gr >= 0 && gr < HIN && gc >= 0 && gc < HIN)
            v = x[(size_t)ci * HIN * HIN + (size_t)gr * HIN + gc];
        pS[ci][kh][c] = v;
    }
    __syncthreads();

    // im2col into Ah/Al
    {
        int n = tid >> 2, qg = tid & 3;
        unsigned uh[4], ul[4];
        #pragma unroll
        for (int e2 = 0; e2 < 4; ++e2) {
            ushort_t hh[2], ll[2];
            #pragma unroll
            for (int s = 0; s < 2; ++s) {
                int q = qg * 8 + e2 * 2 + s;
                float v = 0.f;
                if (q < 27) {
                    int ci = q / 9, r = (q % 9) / 3, kw = q % 3;
                    v = pS[ci][r][2 * n + kw];
                }
                _Float16 h = (_Float16)v;
                _Float16 l = (_Float16)(v - (float)h);
                hh[s] = f16bits(h); ll[s] = f16bits(l);
            }
            uh[e2] = (unsigned)hh[0] | ((unsigned)hh[1] << 16);
            ul[e2] = (unsigned)ll[0] | ((unsigned)ll[1] << 16);
        }
        *(uint4*)&Ah[n][qg * 8] = *(uint4*)uh;
        *(uint4*)&Al[n][qg * 8] = *(uint4*)ul;
    }
    __syncthreads();

    int lane = tid & 63, w = tid >> 6;
    int la = lane & 15, lg = lane >> 4;
    int wbase = w * 64;

    f16x8 ah[4], al[4], bh[4], bl[4];
    #pragma unroll
    for (int i = 0; i < 4; ++i) {
        ah[i] = *(const f16x8*)&Ah[i * 16 + la][lg * 8];
        al[i] = *(const f16x8*)&Al[i * 16 + la][lg * 8];
    }
    #pragma unroll
    for (int j = 0; j < 4; ++j) {
        int co = wbase + j * 16 + la;
        bh[j] = *(const f16x8*)&Wh[co * 32 + lg * 8];
        bl[j] = *(const f16x8*)&Wl[co * 32 + lg * 8];
    }

    f32x4 acc[4][4];
    #pragma unroll
    for (int i = 0; i < 4; ++i)
        #pragma unroll
        for (int j = 0; j < 4; ++j) acc[i][j] = (f32x4)0.f;

    #pragma unroll
    for (int i = 0; i < 4; ++i)
        #pragma unroll
        for (int j = 0; j < 4; ++j) {
            acc[i][j] = __builtin_amdgcn_mfma_f32_16x16x32_f16(ah[i], bh[j], acc[i][j], 0, 0, 0);
            acc[i][j] = __builtin_amdgcn_mfma_f32_16x16x32_f16(al[i], bh[j], acc[i][j], 0, 0, 0);
            acc[i][j] = __builtin_amdgcn_mfma_f32_16x16x32_f16(ah[i], bl[j], acc[i][j], 0, 0, 0);
        }

    float bj[4];
    #pragma unroll
    for (int j = 0; j < 4; ++j) bj[j] = bS[wbase + j * 16 + la];

    int pixbase = oh * HF + ow0;
    float s[4][4];
    #pragma unroll
    for (int i = 0; i < 4; ++i)
        #pragma unroll
        for (int r = 0; r < 4; ++r) s[i][r] = 0.f;

    #pragma unroll
    for (int i = 0; i < 4; ++i) {
        #pragma unroll
        for (int j = 0; j < 4; ++j) {
            int co = wbase + j * 16 + la;
            #pragma unroll
            for (int r = 0; r < 4; ++r) {
                float v = fmaxf(acc[i][j][r] + bj[j], 0.f);
                if (!isA) {
                    _Float16 h = (_Float16)v;
                    _Float16 l = (_Float16)(v - (float)h);
                    unsigned pk = (unsigned)f16bits(h) | ((unsigned)f16bits(l) << 16);
                    size_t addr = ((size_t)b * NF + pixbase + i * 16 + lg * 4 + r) * COUT + co;
                    fBT[addr] = pk;
                }
                s[i][r] += isA ? v : v * v;
            }
        }
    }
    #pragma unroll
    for (int i = 0; i < 4; ++i)
        #pragma unroll
        for (int r = 0; r < 4; ++r) {
            float v = s[i][r];
            v += __shfl_xor(v, 1, 64);
            v += __shfl_xor(v, 2, 64);
            v += __shfl_xor(v, 4, 64);
            v += __shfl_xor(v, 8, 64);
            s[i][r] = v;
        }
    if (la == 0) {
        #pragma unroll
        for (int i = 0; i < 4; ++i)
            #pragma unroll
            for (int r = 0; r < 4; ++r)
                redS[w][i * 16 + lg * 4 + r] = s[i][r];
    }
    __syncthreads();
    if (tid < 64) {
        float tot = redS[0][tid] + redS[1][tid] + redS[2][tid] + redS[3][tid];
        size_t addr = (size_t)b * NF + pixbase + tid;
        if (isA) resp[addr] = tot;
        else     normB[addr] = tot;
    }
}

// =====================================================================
// Fused select: pool argmax (wave 0) + descriptor conv-recompute (fp32 exact).
// =====================================================================
__global__ __launch_bounds__(256) void select_kernel(
        const float* __restrict__ resp,
        const float* __restrict__ xA, const float* __restrict__ W,
        const float* __restrict__ bias,
        int* __restrict__ idxA,
        ushort_t* __restrict__ desc_h, ushort_t* __restrict__ desc_l,
        float* __restrict__ normA)
{
    __shared__ float patch[27];
    __shared__ float red[4];
    __shared__ int   sidx;

    int bk = blockIdx.x;              // b*KK + k
    int b = bk >> 8, kIdx = bk & 255;
    int t = threadIdx.x;

    if (t < 64) {
        int kr = kIdx >> 4, kc = kIdx & 15;
        int lr = t >> 3, lc = t & 7;
        int row = kr * 8 + lr, col = kc * 8 + lc;
        float bv = resp[(size_t)b * NF + (size_t)row * HF + col];
        int best = t;
        for (int off = 32; off > 0; off >>= 1) {
            float ov = __shfl_down(bv, off, 64);
            int   oi = __shfl_down(best, off, 64);
            if (ov > bv || (ov == bv && oi < best)) { bv = ov; best = oi; }
        }
        if (t == 0) {
            int r = kr * 8 + (best >> 3), c = kc * 8 + (best & 7);
            int idx = r * HF + c;
            idxA[bk] = idx;
            sidx = idx;
        }
    }
    __syncthreads();
    int idx = sidx;
    int oh = idx >> 7, ow = idx & 127;

    if (t < 27) {
        int ci = t / 9, kh = (t % 9) / 3, kw = t % 3;
        int ir = oh * 2 - 1 + kh, ic = ow * 2 - 1 + kw;
        float v = 0.f;
        if (ir >= 0 && ir < HIN && ic >= 0 && ic < HIN)
            v = xA[((size_t)b * CIN + ci) * HIN * HIN + (size_t)ir * HIN + ic];
        patch[t] = v;
    }
    __syncthreads();

    float v = bias[t];
    const float* w = &W[t * 27];
    #pragma unroll
    for (int q = 0; q < 27; ++q) v = fmaf(patch[q], w[q], v);
    v = fmaxf(v, 0.f);

    _Float16 h = (_Float16)v;
    _Float16 l = (_Float16)(v - (float)h);
    desc_h[(size_t)bk * COUT + t] = f16bits(h);
    desc_l[(size_t)bk * COUT + t] = f16bits(l);

    float s = v * v;
    for (int off = 32; off > 0; off >>= 1) s += __shfl_down(s, off, 64);
    if ((t & 63) == 0) red[t >> 6] = s;
    __syncthreads();
    if (t == 0) normA[bk] = red[0] + red[1] + red[2] + red[3];
}

// =====================================================================
// MFMA kNN, barrier-free K-loop: A-fragments loaded directly from fBT
// [n][c] (2 x uint4 per i-tile, unpacked h/l via bit ops); desc fragments
// direct from global (L2-hot). 3-pass f16x2 split. No LDS staging.
// =====================================================================
__global__ __launch_bounds__(256) void knn_kernel(
        const unsigned* __restrict__ fBT,
        const ushort_t* __restrict__ desc_h, const ushort_t* __restrict__ desc_l,
        const float* __restrict__ normA, const float* __restrict__ normB,
        unsigned long long* __restrict__ scratch)
{
    __shared__ float nAS[KK];

    int nb = blockIdx.x;      // 0..255
    int b  = blockIdx.y;      // 0..3
    int tid = threadIdx.x;
    int lane = tid & 63, w = tid >> 6;
    int n0 = nb * 64;

    nAS[tid] = normA[b * KK + tid];
    __syncthreads();

    int la = lane & 15, lg = lane >> 4;
    int kw0 = w * 64;

    const unsigned* fp = fBT + ((size_t)b * NF + n0) * COUT;
    const ushort_t* dh = desc_h + (size_t)b * KK * COUT;
    const ushort_t* dl = desc_l + (size_t)b * KK * COUT;

    f32x4 acc[4][4];
    #pragma unroll
    for (int i = 0; i < 4; ++i)
        #pragma unroll
        for (int j = 0; j < 4; ++j) acc[i][j] = (f32x4)0.f;

    for (int cc = 0; cc < COUT; cc += 32) {
        f16x8 bh[4], bl[4];
        #pragma unroll
        for (int j = 0; j < 4; ++j) {
            size_t off = (size_t)(kw0 + j * 16 + la) * COUT + cc + lg * 8;
            bh[j] = *(const f16x8*)&dh[off];
            bl[j] = *(const f16x8*)&dl[off];
        }
        #pragma unroll
        for (int i = 0; i < 4; ++i) {
            const uint4* pr = (const uint4*)&fp[(size_t)(i * 16 + la) * COUT + cc + lg * 8];
            uint4 u0 = pr[0], u1 = pr[1];
            uint4 hv, lv;
            hv.x = (u0.x & 0xffffu) | (u0.y << 16);
            lv.x = (u0.x >> 16)     | (u0.y & 0xffff0000u);
            hv.y = (u0.z & 0xffffu) | (u0.w << 16);
            lv.y = (u0.z >> 16)     | (u0.w & 0xffff0000u);
            hv.z = (u1.x & 0xffffu) | (u1.y << 16);
            lv.z = (u1.x >> 16)     | (u1.y & 0xffff0000u);
            hv.w = (u1.z & 0xffffu) | (u1.w << 16);
            lv.w = (u1.z >> 16)     | (u1.w & 0xffff0000u);
            f16x8 ah = __builtin_bit_cast(f16x8, hv);
            f16x8 al = __builtin_bit_cast(f16x8, lv);
            #pragma unroll
            for (int j = 0; j < 4; ++j) {
                acc[i][j] = __builtin_amdgcn_mfma_f32_16x16x32_f16(ah, bh[j], acc[i][j], 0, 0, 0);
                acc[i][j] = __builtin_amdgcn_mfma_f32_16x16x32_f16(al, bh[j], acc[i][j], 0, 0, 0);
                acc[i][j] = __builtin_amdgcn_mfma_f32_16x16x32_f16(ah, bl[j], acc[i][j], 0, 0, 0);
            }
        }
    }

    // ---- epilogue: dist + per-k argmin ----
    float nBv[4][4];
    #pragma unroll
    for (int i = 0; i < 4; ++i) {
        f32x4 t4 = *(const f32x4*)&normB[(size_t)b * NF + n0 + i * 16 + lg * 4];
        nBv[i][0] = t4[0]; nBv[i][1] = t4[1]; nBv[i][2] = t4[2]; nBv[i][3] = t4[3];
    }
    #pragma unroll
    for (int j = 0; j < 4; ++j) {
        int kl = kw0 + j * 16 + la;
        float nAv = nAS[kl];
        unsigned long long best = ~0ull;
        #pragma unroll
        for (int i = 0; i < 4; ++i)
            #pragma unroll
            for (int r = 0; r < 4; ++r) {
                int n = n0 + i * 16 + lg * 4 + r;
                float d = fmaf(-2.f, acc[i][j][r], nAv) + nBv[i][r];
                unsigned u = __float_as_uint(d);
                u = (u & 0x80000000u) ? ~u : (u | 0x80000000u);
                unsigned long long key = ((unsigned long long)u << 32) | (unsigned)n;
                best = u64min(best, key);
            }
        best = u64min(best, shfl_xor_u64(best, 16));
        best = u64min(best, shfl_xor_u64(best, 32));
        if (lg == 0)
            scratch[(size_t)(b * KK + kl) * 256 + nb] = best;
    }
}

// =====================================================================
// Final argmin reduce over the 256 nb-blocks -> minN[b*KK + k]
// =====================================================================
__global__ __launch_bounds__(64) void reduce_kernel(
        const unsigned long long* __restrict__ scratch, int* __restrict__ minN)
{
    int bk = blockIdx.x;              // b*KK + k
    int t = threadIdx.x;
    const unsigned long long* s = scratch + (size_t)bk * 256;
    unsigned long long best = s[t];
    best = u64min(best, s[t + 64]);
    best = u64min(best, s[t + 128]);
    best = u64min(best, s[t + 192]);
    for (int off = 32; off > 0; off >>= 1)
        best = u64min(best, shfl_down_u64(best, off));
    if (t == 0) minN[bk] = (int)(best & 0xffffffffULL);
}

// =====================================================================
// Two tiny MLPs: x(256) -> 128 relu -> 1. block per (b, which), 128 threads.
// =====================================================================
__global__ __launch_bounds__(128) void mlp_kernel(
        const int* __restrict__ idxA, const int* __restrict__ minN,
        const float* __restrict__ W1r, const float* __restrict__ b1r,
        const float* __restrict__ W2r, const float* __restrict__ b2r,
        const float* __restrict__ W1c, const float* __restrict__ b1c,
        const float* __restrict__ W2c, const float* __restrict__ b2c,
        float* __restrict__ out)
{
    __shared__ float xS[KK];
    __shared__ float red[2];
    int blk = blockIdx.x;            // b*2 + which
    int b = blk >> 1, which = blk & 1;
    int t = threadIdx.x;             // 0..127

    for (int k = t; k < KK; k += 128) {
        int ia = idxA[b * KK + k];
        int nn = minN[b * KK + k];
        int rowA = ia >> 7, colA = ia & 127;
        int rowB = nn >> 7, colB = nn & 127;
        xS[k] = (which == 0) ? (float)(rowB - rowA) : (float)(colA - colB);
    }
    __syncthreads();

    const float* W1 = which ? W1c : W1r;
    const float* b1 = which ? b1c : b1r;
    const float* W2 = which ? W2c : W2r;
    const float* b2 = which ? b2c : b2r;

    float h = b1[t];
    for (int k = 0; k < KK; ++k) h = fmaf(xS[k], W1[k * HID + t], h);
    h = fmaxf(h, 0.f);
    float pv = h * W2[t];
    for (int off = 32; off > 0; off >>= 1) pv += __shfl_down(pv, off, 64);
    if ((t & 63) == 0) red[t >> 6] = pv;
    __syncthreads();
    if (t == 0) out[b * 2 + which] = red[0] + red[1] + b2[0];
}

// =====================================================================
extern "C" void kernel_launch(void* const* d_in, const int* in_sizes, int n_in,
                              void* d_out, int out_size, void* d_ws, size_t ws_size,
                              hipStream_t stream)
{
    const float* xA  = (const float*)d_in[0];
    const float* xB  = (const float*)d_in[1];
    const float* Wc  = (const float*)d_in[2];
    const float* bc  = (const float*)d_in[3];
    const float* W1r = (const float*)d_in[4];
    const float* b1r = (const float*)d_in[5];
    const float* W2r = (const float*)d_in[6];
    const float* b2r = (const float*)d_in[7];
    const float* W1c = (const float*)d_in[8];
    const float* b1c = (const float*)d_in[9];
    const float* W2c = (const float*)d_in[10];
    const float* b2c = (const float*)d_in[11];
    float* out = (float*)d_out;

    char* ws = (char*)d_ws;
    unsigned long long* scratch = (unsigned long long*)ws; ws += (size_t)NB * KK * 256 * 8;
    int*   idxA   = (int*)ws;      ws += (size_t)NB * KK * 4;
    int*   minN   = (int*)ws;      ws += (size_t)NB * KK * 4;
    float* normA  = (float*)ws;    ws += (size_t)NB * KK * 4;
    float* resp   = (float*)ws;    ws += (size_t)NB * NF * 4;
    float* normB  = (float*)ws;    ws += (size_t)NB * NF * 4;
    ushort_t* desc_h = (ushort_t*)ws; ws += (size_t)NB * KK * COUT * 2;
    ushort_t* desc_l = (ushort_t*)ws; ws += (size_t)NB * KK * COUT * 2;
    ushort_t* Wh  = (ushort_t*)ws; ws += (size_t)COUT * 32 * 2;
    ushort_t* Wl  = (ushort_t*)ws; ws += (size_t)COUT * 32 * 2;
    unsigned* fBT = (unsigned*)ws; ws += (size_t)NB * COUT * NF * 4;

    prep_kernel  <<<1, 256, 0, stream>>>(Wc, Wh, Wl);
    conv_kernel  <<<2048, 256, 0, stream>>>(xA, xB, Wh, Wl, bc, fBT, resp, normB);
    select_kernel<<<NB * KK, 256, 0, stream>>>(resp, xA, Wc, bc, idxA, desc_h, desc_l, normA);
    knn_kernel   <<<dim3(256, NB), 256, 0, stream>>>(fBT, desc_h, desc_l, normA, normB, scratch);
    reduce_kernel<<<NB * KK, 64, 0, stream>>>(scratch, minN);
    mlp_kernel   <<<8, 128, 0, stream>>>(idxA, minN,
                                         W1r, b1r, W2r, b2r,
                                         W1c, b1c, W2c, b2c, out);
}

// Round 7
// 99.531 us; speedup vs baseline: 1.1865x; 1.1865x over previous
//
#include <hip/hip_runtime.h>
#include <stdint.h>

// ---- problem constants ----
constexpr int NB   = 4;      // batch
constexpr int CIN  = 3;
constexpr int HIN  = 256;
constexpr int COUT = 256;
constexpr int HF   = 128;              // feature H=W after stride-2 conv
constexpr int NF   = HF * HF;          // 16384
constexpr int KADM = 16;
constexpr int KK   = KADM * KADM;      // 256 descriptors
constexpr int HID  = 128;              // MLP hidden

typedef unsigned short ushort_t;
typedef __attribute__((ext_vector_type(8))) _Float16 f16x8;
typedef __attribute__((ext_vector_type(4))) float    f32x4;

__device__ inline unsigned long long shfl_xor_u64(unsigned long long v, int m) {
    unsigned lo = __shfl_xor((unsigned)v, m, 64);
    unsigned hi = __shfl_xor((unsigned)(v >> 32), m, 64);
    return ((unsigned long long)hi << 32) | lo;
}
__device__ inline unsigned long long shfl_down_u64(unsigned long long v, int off) {
    unsigned lo = __shfl_down((unsigned)v, off, 64);
    unsigned hi = __shfl_down((unsigned)(v >> 32), off, 64);
    return ((unsigned long long)hi << 32) | lo;
}
__device__ inline unsigned long long u64min(unsigned long long a, unsigned long long b) {
    return a < b ? a : b;
}
__device__ inline ushort_t f16bits(_Float16 h) { return __builtin_bit_cast(ushort_t, h); }

// =====================================================================
// Prep: split conv weights into f16 hi/lo, K padded 27->32.
// =====================================================================
__global__ __launch_bounds__(256) void prep_kernel(
        const float* __restrict__ W, ushort_t* __restrict__ Wh, ushort_t* __restrict__ Wl)
{
    int t = threadIdx.x;            // co
    #pragma unroll
    for (int q = 0; q < 32; ++q) {
        float v = (q < 27) ? W[t * 27 + q] : 0.f;
        _Float16 h = (_Float16)v;
        _Float16 l = (_Float16)(v - (float)h);
        Wh[t * 32 + q] = f16bits(h);
        Wl[t * 32 + q] = f16bits(l);
    }
}

// =====================================================================
// Conv as MFMA im2col GEMM: [64 pixels x 32(K)] x [32 x 256 channels].
// f16x2 split, 3 passes: xh*wh + xl*wh + xh*wl.
// A images: emit resp = sum_c relu(v). B images: fBT[n][c] packed h|l<<16
// (channel-contig so knn staging is coalesced) + normB.
// =====================================================================
__global__ __launch_bounds__(256) void conv_kernel(
        const float* __restrict__ xA, const float* __restrict__ xB,
        const ushort_t* __restrict__ Wh, const ushort_t* __restrict__ Wl,
        const float* __restrict__ bias,
        unsigned* __restrict__ fBT, float* __restrict__ resp, float* __restrict__ normB)
{
    __shared__ float    pS[CIN][3][132];    // input rows
    __shared__ ushort_t Ah[64][40];         // im2col hi, 80B row stride
    __shared__ ushort_t Al[64][40];         // im2col lo
    __shared__ float    bS[COUT];
    __shared__ float    redS[4][64];

    int blk = blockIdx.x;            // 0..2047
    int img = blk >> 8;              // 0..7
    int rem = blk & 255;
    int oh  = rem >> 1;
    int ow0 = (rem & 1) << 6;
    bool isA = (img < 4);
    int b = img & 3;
    const float* x = isA ? (xA + (size_t)b * CIN * HIN * HIN)
                         : (xB + (size_t)b * CIN * HIN * HIN);
    int tid = threadIdx.x;

    bS[tid] = bias[tid];

    for (int i = tid; i < CIN * 3 * 129; i += 256) {
        int ci = i / (3 * 129);
        int r2 = i % (3 * 129);
        int kh = r2 / 129, c = r2 % 129;
        int gr = 2 * oh - 1 + kh, gc = 2 * ow0 - 1 + c;
        float v = 0.f;
        if (gr >= 0 && gr < HIN && gc >= 0 && gc < HIN)
            v = x[(size_t)ci * HIN * HIN + (size_t)gr * HIN + gc];
        pS[ci][kh][c] = v;
    }
    __syncthreads();

    // im2col into Ah/Al
    {
        int n = tid >> 2, qg = tid & 3;
        unsigned uh[4], ul[4];
        #pragma unroll
        for (int e2 = 0; e2 < 4; ++e2) {
            ushort_t hh[2], ll[2];
            #pragma unroll
            for (int s = 0; s < 2; ++s) {
                int q = qg * 8 + e2 * 2 + s;
                float v = 0.f;
                if (q < 27) {
                    int ci = q / 9, r = (q % 9) / 3, kw = q % 3;
                    v = pS[ci][r][2 * n + kw];
                }
                _Float16 h = (_Float16)v;
                _Float16 l = (_Float16)(v - (float)h);
                hh[s] = f16bits(h); ll[s] = f16bits(l);
            }
            uh[e2] = (unsigned)hh[0] | ((unsigned)hh[1] << 16);
            ul[e2] = (unsigned)ll[0] | ((unsigned)ll[1] << 16);
        }
        *(uint4*)&Ah[n][qg * 8] = *(uint4*)uh;
        *(uint4*)&Al[n][qg * 8] = *(uint4*)ul;
    }
    __syncthreads();

    int lane = tid & 63, w = tid >> 6;
    int la = lane & 15, lg = lane >> 4;
    int wbase = w * 64;

    f16x8 ah[4], al[4], bh[4], bl[4];
    #pragma unroll
    for (int i = 0; i < 4; ++i) {
        ah[i] = *(const f16x8*)&Ah[i * 16 + la][lg * 8];
        al[i] = *(const f16x8*)&Al[i * 16 + la][lg * 8];
    }
    #pragma unroll
    for (int j = 0; j < 4; ++j) {
        int co = wbase + j * 16 + la;
        bh[j] = *(const f16x8*)&Wh[co * 32 + lg * 8];
        bl[j] = *(const f16x8*)&Wl[co * 32 + lg * 8];
    }

    f32x4 acc[4][4];
    #pragma unroll
    for (int i = 0; i < 4; ++i)
        #pragma unroll
        for (int j = 0; j < 4; ++j) acc[i][j] = (f32x4)0.f;

    #pragma unroll
    for (int i = 0; i < 4; ++i)
        #pragma unroll
        for (int j = 0; j < 4; ++j) {
            acc[i][j] = __builtin_amdgcn_mfma_f32_16x16x32_f16(ah[i], bh[j], acc[i][j], 0, 0, 0);
            acc[i][j] = __builtin_amdgcn_mfma_f32_16x16x32_f16(al[i], bh[j], acc[i][j], 0, 0, 0);
            acc[i][j] = __builtin_amdgcn_mfma_f32_16x16x32_f16(ah[i], bl[j], acc[i][j], 0, 0, 0);
        }

    float bj[4];
    #pragma unroll
    for (int j = 0; j < 4; ++j) bj[j] = bS[wbase + j * 16 + la];

    int pixbase = oh * HF + ow0;
    float s[4][4];
    #pragma unroll
    for (int i = 0; i < 4; ++i)
        #pragma unroll
        for (int r = 0; r < 4; ++r) s[i][r] = 0.f;

    #pragma unroll
    for (int i = 0; i < 4; ++i) {
        #pragma unroll
        for (int j = 0; j < 4; ++j) {
            int co = wbase + j * 16 + la;
            #pragma unroll
            for (int r = 0; r < 4; ++r) {
                float v = fmaxf(acc[i][j][r] + bj[j], 0.f);
                if (!isA) {
                    _Float16 h = (_Float16)v;
                    _Float16 l = (_Float16)(v - (float)h);
                    unsigned pk = (unsigned)f16bits(h) | ((unsigned)f16bits(l) << 16);
                    size_t addr = ((size_t)b * NF + pixbase + i * 16 + lg * 4 + r) * COUT + co;
                    fBT[addr] = pk;
                }
                s[i][r] += isA ? v : v * v;
            }
        }
    }
    #pragma unroll
    for (int i = 0; i < 4; ++i)
        #pragma unroll
        for (int r = 0; r < 4; ++r) {
            float v = s[i][r];
            v += __shfl_xor(v, 1, 64);
            v += __shfl_xor(v, 2, 64);
            v += __shfl_xor(v, 4, 64);
            v += __shfl_xor(v, 8, 64);
            s[i][r] = v;
        }
    if (la == 0) {
        #pragma unroll
        for (int i = 0; i < 4; ++i)
            #pragma unroll
            for (int r = 0; r < 4; ++r)
                redS[w][i * 16 + lg * 4 + r] = s[i][r];
    }
    __syncthreads();
    if (tid < 64) {
        float tot = redS[0][tid] + redS[1][tid] + redS[2][tid] + redS[3][tid];
        size_t addr = (size_t)b * NF + pixbase + tid;
        if (isA) resp[addr] = tot;
        else     normB[addr] = tot;
    }
}

// =====================================================================
// Fused select: pool argmax (wave 0) + descriptor conv-recompute (fp32 exact).
// =====================================================================
__global__ __launch_bounds__(256) void select_kernel(
        const float* __restrict__ resp,
        const float* __restrict__ xA, const float* __restrict__ W,
        const float* __restrict__ bias,
        int* __restrict__ idxA,
        ushort_t* __restrict__ desc_h, ushort_t* __restrict__ desc_l,
        float* __restrict__ normA)
{
    __shared__ float patch[27];
    __shared__ float red[4];
    __shared__ int   sidx;

    int bk = blockIdx.x;              // b*KK + k
    int b = bk >> 8, kIdx = bk & 255;
    int t = threadIdx.x;

    if (t < 64) {
        int kr = kIdx >> 4, kc = kIdx & 15;
        int lr = t >> 3, lc = t & 7;
        int row = kr * 8 + lr, col = kc * 8 + lc;
        float bv = resp[(size_t)b * NF + (size_t)row * HF + col];
        int best = t;
        for (int off = 32; off > 0; off >>= 1) {
            float ov = __shfl_down(bv, off, 64);
            int   oi = __shfl_down(best, off, 64);
            if (ov > bv || (ov == bv && oi < best)) { bv = ov; best = oi; }
        }
        if (t == 0) {
            int r = kr * 8 + (best >> 3), c = kc * 8 + (best & 7);
            int idx = r * HF + c;
            idxA[bk] = idx;
            sidx = idx;
        }
    }
    __syncthreads();
    int idx = sidx;
    int oh = idx >> 7, ow = idx & 127;

    if (t < 27) {
        int ci = t / 9, kh = (t % 9) / 3, kw = t % 3;
        int ir = oh * 2 - 1 + kh, ic = ow * 2 - 1 + kw;
        float v = 0.f;
        if (ir >= 0 && ir < HIN && ic >= 0 && ic < HIN)
            v = xA[((size_t)b * CIN + ci) * HIN * HIN + (size_t)ir * HIN + ic];
        patch[t] = v;
    }
    __syncthreads();

    float v = bias[t];
    const float* w = &W[t * 27];
    #pragma unroll
    for (int q = 0; q < 27; ++q) v = fmaf(patch[q], w[q], v);
    v = fmaxf(v, 0.f);

    _Float16 h = (_Float16)v;
    _Float16 l = (_Float16)(v - (float)h);
    desc_h[(size_t)bk * COUT + t] = f16bits(h);
    desc_l[(size_t)bk * COUT + t] = f16bits(l);

    float s = v * v;
    for (int off = 32; off > 0; off >>= 1) s += __shfl_down(s, off, 64);
    if ((t & 63) == 0) red[t >> 6] = s;
    __syncthreads();
    if (t == 0) normA[bk] = red[0] + red[1] + red[2] + red[3];
}

// =====================================================================
// MFMA kNN: coalesced staging (fBT [n][c]) -> LDS tile -> fragments.
// Register-prefetch pipeline: chunk cc+32 loads issue during chunk cc MFMAs.
// 3-pass f16x2 split. Desc fragments direct from global (L2-hot).
// =====================================================================
__global__ __launch_bounds__(256) void knn_kernel(
        const unsigned* __restrict__ fBT,
        const ushort_t* __restrict__ desc_h, const ushort_t* __restrict__ desc_l,
        const float* __restrict__ normA, const float* __restrict__ normB,
        unsigned long long* __restrict__ scratch)
{
    __shared__ ushort_t Hs[64][40];   // hi, 80B rows (measured-cheap banks)
    __shared__ ushort_t Ls[64][40];   // lo
    __shared__ float nAS[KK];

    int nb = blockIdx.x;      // 0..255
    int b  = blockIdx.y;      // 0..3
    int tid = threadIdx.x;
    int lane = tid & 63, w = tid >> 6;
    int n0 = nb * 64;

    nAS[tid] = normA[b * KK + tid];

    int la = lane & 15, lg = lane >> 4;
    int kw0 = w * 64;

    const unsigned* fp = fBT + ((size_t)b * NF + n0) * COUT;
    const ushort_t* dh = desc_h + (size_t)b * KK * COUT;
    const ushort_t* dl = desc_l + (size_t)b * KK * COUT;

    // staging mapping: thread -> (pixel, channel-quad), 2 iters
    int sp = tid >> 3;        // 0..31
    int sq = tid & 7;         // channel-quad (4 u32)

    f32x4 acc[4][4];
    #pragma unroll
    for (int i = 0; i < 4; ++i)
        #pragma unroll
        for (int j = 0; j < 4; ++j) acc[i][j] = (f32x4)0.f;

    uint4 st0 = *(const uint4*)&fp[(size_t)sp * COUT + sq * 4];
    uint4 st1 = *(const uint4*)&fp[(size_t)(sp + 32) * COUT + sq * 4];

    for (int cc = 0; cc < COUT; cc += 32) {
        // write staged chunk to LDS (unpack h/l)
        {
            unsigned h0 = (st0.x & 0xffffu) | (st0.y << 16);
            unsigned h1 = (st0.z & 0xffffu) | (st0.w << 16);
            unsigned l0 = (st0.x >> 16)     | (st0.y & 0xffff0000u);
            unsigned l1 = (st0.z >> 16)     | (st0.w & 0xffff0000u);
            *(uint2*)&Hs[sp][sq * 4] = make_uint2(h0, h1);
            *(uint2*)&Ls[sp][sq * 4] = make_uint2(l0, l1);
            h0 = (st1.x & 0xffffu) | (st1.y << 16);
            h1 = (st1.z & 0xffffu) | (st1.w << 16);
            l0 = (st1.x >> 16)     | (st1.y & 0xffff0000u);
            l1 = (st1.z >> 16)     | (st1.w & 0xffff0000u);
            *(uint2*)&Hs[sp + 32][sq * 4] = make_uint2(h0, h1);
            *(uint2*)&Ls[sp + 32][sq * 4] = make_uint2(l0, l1);
        }
        __syncthreads();

        // prefetch next chunk into regs (latency hides under MFMAs)
        if (cc + 32 < COUT) {
            st0 = *(const uint4*)&fp[(size_t)sp * COUT + (cc + 32) + sq * 4];
            st1 = *(const uint4*)&fp[(size_t)(sp + 32) * COUT + (cc + 32) + sq * 4];
        }

        f16x8 bh[4], bl[4];
        #pragma unroll
        for (int j = 0; j < 4; ++j) {
            size_t off = (size_t)(kw0 + j * 16 + la) * COUT + cc + lg * 8;
            bh[j] = *(const f16x8*)&dh[off];
            bl[j] = *(const f16x8*)&dl[off];
        }
        #pragma unroll
        for (int i = 0; i < 4; ++i) {
            f16x8 ah = *(const f16x8*)&Hs[i * 16 + la][lg * 8];
            f16x8 al = *(const f16x8*)&Ls[i * 16 + la][lg * 8];
            #pragma unroll
            for (int j = 0; j < 4; ++j) {
                acc[i][j] = __builtin_amdgcn_mfma_f32_16x16x32_f16(ah, bh[j], acc[i][j], 0, 0, 0);
                acc[i][j] = __builtin_amdgcn_mfma_f32_16x16x32_f16(al, bh[j], acc[i][j], 0, 0, 0);
                acc[i][j] = __builtin_amdgcn_mfma_f32_16x16x32_f16(ah, bl[j], acc[i][j], 0, 0, 0);
            }
        }
        __syncthreads();
    }

    // ---- epilogue: dist + per-k argmin ----
    float nBv[4][4];
    #pragma unroll
    for (int i = 0; i < 4; ++i) {
        f32x4 t4 = *(const f32x4*)&normB[(size_t)b * NF + n0 + i * 16 + lg * 4];
        nBv[i][0] = t4[0]; nBv[i][1] = t4[1]; nBv[i][2] = t4[2]; nBv[i][3] = t4[3];
    }
    #pragma unroll
    for (int j = 0; j < 4; ++j) {
        int kl = kw0 + j * 16 + la;
        float nAv = nAS[kl];
        unsigned long long best = ~0ull;
        #pragma unroll
        for (int i = 0; i < 4; ++i)
            #pragma unroll
            for (int r = 0; r < 4; ++r) {
                int n = n0 + i * 16 + lg * 4 + r;
                float d = fmaf(-2.f, acc[i][j][r], nAv) + nBv[i][r];
                unsigned u = __float_as_uint(d);
                u = (u & 0x80000000u) ? ~u : (u | 0x80000000u);
                unsigned long long key = ((unsigned long long)u << 32) | (unsigned)n;
                best = u64min(best, key);
            }
        best = u64min(best, shfl_xor_u64(best, 16));
        best = u64min(best, shfl_xor_u64(best, 32));
        if (lg == 0)
            scratch[(size_t)(b * KK + kl) * 256 + nb] = best;
    }
}

// =====================================================================
// Final argmin reduce over the 256 nb-blocks -> minN[b*KK + k]
// =====================================================================
__global__ __launch_bounds__(64) void reduce_kernel(
        const unsigned long long* __restrict__ scratch, int* __restrict__ minN)
{
    int bk = blockIdx.x;              // b*KK + k
    int t = threadIdx.x;
    const unsigned long long* s = scratch + (size_t)bk * 256;
    unsigned long long best = s[t];
    best = u64min(best, s[t + 64]);
    best = u64min(best, s[t + 128]);
    best = u64min(best, s[t + 192]);
    for (int off = 32; off > 0; off >>= 1)
        best = u64min(best, shfl_down_u64(best, off));
    if (t == 0) minN[bk] = (int)(best & 0xffffffffULL);
}

// =====================================================================
// Two tiny MLPs: x(256) -> 128 relu -> 1. block per (b, which), 128 threads.
// =====================================================================
__global__ __launch_bounds__(128) void mlp_kernel(
        const int* __restrict__ idxA, const int* __restrict__ minN,
        const float* __restrict__ W1r, const float* __restrict__ b1r,
        const float* __restrict__ W2r, const float* __restrict__ b2r,
        const float* __restrict__ W1c, const float* __restrict__ b1c,
        const float* __restrict__ W2c, const float* __restrict__ b2c,
        float* __restrict__ out)
{
    __shared__ float xS[KK];
    __shared__ float red[2];
    int blk = blockIdx.x;            // b*2 + which
    int b = blk >> 1, which = blk & 1;
    int t = threadIdx.x;             // 0..127

    for (int k = t; k < KK; k += 128) {
        int ia = idxA[b * KK + k];
        int nn = minN[b * KK + k];
        int rowA = ia >> 7, colA = ia & 127;
        int rowB = nn >> 7, colB = nn & 127;
        xS[k] = (which == 0) ? (float)(rowB - rowA) : (float)(colA - colB);
    }
    __syncthreads();

    const float* W1 = which ? W1c : W1r;
    const float* b1 = which ? b1c : b1r;
    const float* W2 = which ? W2c : W2r;
    const float* b2 = which ? b2c : b2r;

    float h = b1[t];
    for (int k = 0; k < KK; ++k) h = fmaf(xS[k], W1[k * HID + t], h);
    h = fmaxf(h, 0.f);
    float pv = h * W2[t];
    for (int off = 32; off > 0; off >>= 1) pv += __shfl_down(pv, off, 64);
    if ((t & 63) == 0) red[t >> 6] = pv;
    __syncthreads();
    if (t == 0) out[b * 2 + which] = red[0] + red[1] + b2[0];
}

// =====================================================================
extern "C" void kernel_launch(void* const* d_in, const int* in_sizes, int n_in,
                              void* d_out, int out_size, void* d_ws, size_t ws_size,
                              hipStream_t stream)
{
    const float* xA  = (const float*)d_in[0];
    const float* xB  = (const float*)d_in[1];
    const float* Wc  = (const float*)d_in[2];
    const float* bc  = (const float*)d_in[3];
    const float* W1r = (const float*)d_in[4];
    const float* b1r = (const float*)d_in[5];
    const float* W2r = (const float*)d_in[6];
    const float* b2r = (const float*)d_in[7];
    const float* W1c = (const float*)d_in[8];
    const float* b1c = (const float*)d_in[9];
    const float* W2c = (const float*)d_in[10];
    const float* b2c = (const float*)d_in[11];
    float* out = (float*)d_out;

    char* ws = (char*)d_ws;
    unsigned long long* scratch = (unsigned long long*)ws; ws += (size_t)NB * KK * 256 * 8;
    int*   idxA   = (int*)ws;      ws += (size_t)NB * KK * 4;
    int*   minN   = (int*)ws;      ws += (size_t)NB * KK * 4;
    float* normA  = (float*)ws;    ws += (size_t)NB * KK * 4;
    float* resp   = (float*)ws;    ws += (size_t)NB * NF * 4;
    float* normB  = (float*)ws;    ws += (size_t)NB * NF * 4;
    ushort_t* desc_h = (ushort_t*)ws; ws += (size_t)NB * KK * COUT * 2;
    ushort_t* desc_l = (ushort_t*)ws; ws += (size_t)NB * KK * COUT * 2;
    ushort_t* Wh  = (ushort_t*)ws; ws += (size_t)COUT * 32 * 2;
    ushort_t* Wl  = (ushort_t*)ws; ws += (size_t)COUT * 32 * 2;
    unsigned* fBT = (unsigned*)ws; ws += (size_t)NB * COUT * NF * 4;

    prep_kernel  <<<1, 256, 0, stream>>>(Wc, Wh, Wl);
    conv_kernel  <<<2048, 256, 0, stream>>>(xA, xB, Wh, Wl, bc, fBT, resp, normB);
    select_kernel<<<NB * KK, 256, 0, stream>>>(resp, xA, Wc, bc, idxA, desc_h, desc_l, normA);
    knn_kernel   <<<dim3(256, NB), 256, 0, stream>>>(fBT, desc_h, desc_l, normA, normB, scratch);
    reduce_kernel<<<NB * KK, 64, 0, stream>>>(scratch, minN);
    mlp_kernel   <<<8, 128, 0, stream>>>(idxA, minN,
                                         W1r, b1r, W2r, b2r,
                                         W1c, b1c, W2c, b2c, out);
}

// Round 8
// 80.556 us; speedup vs baseline: 1.4660x; 1.2356x over previous
//
#include <hip/hip_runtime.h>
#include <stdint.h>

// ---- problem constants ----
constexpr int NB   = 4;      // batch
constexpr int CIN  = 3;
constexpr int HIN  = 256;
constexpr int COUT = 256;
constexpr int HF   = 128;              // feature H=W after stride-2 conv
constexpr int NF   = HF * HF;          // 16384
constexpr int KADM = 16;
constexpr int KK   = KADM * KADM;      // 256 descriptors
constexpr int HID  = 128;              // MLP hidden
constexpr int FST  = 264;              // fH/fL row stride (f16), 528B = 132dw, 2-way banks

typedef unsigned short ushort_t;
typedef __attribute__((ext_vector_type(8))) _Float16 f16x8;
typedef __attribute__((ext_vector_type(4))) float    f32x4;

__device__ inline unsigned long long shfl_xor_u64(unsigned long long v, int m) {
    unsigned lo = __shfl_xor((unsigned)v, m, 64);
    unsigned hi = __shfl_xor((unsigned)(v >> 32), m, 64);
    return ((unsigned long long)hi << 32) | lo;
}
__device__ inline unsigned long long shfl_down_u64(unsigned long long v, int off) {
    unsigned lo = __shfl_down((unsigned)v, off, 64);
    unsigned hi = __shfl_down((unsigned)(v >> 32), off, 64);
    return ((unsigned long long)hi << 32) | lo;
}
__device__ inline unsigned long long u64min(unsigned long long a, unsigned long long b) {
    return a < b ? a : b;
}
__device__ inline ushort_t f16bits(_Float16 h) { return __builtin_bit_cast(ushort_t, h); }

// =====================================================================
// Prep: split conv weights into f16 hi/lo, K padded 27->32.
// =====================================================================
__global__ __launch_bounds__(256) void prep_kernel(
        const float* __restrict__ W, ushort_t* __restrict__ Wh, ushort_t* __restrict__ Wl)
{
    int t = threadIdx.x;            // co
    #pragma unroll
    for (int q = 0; q < 32; ++q) {
        float v = (q < 27) ? W[t * 27 + q] : 0.f;
        _Float16 h = (_Float16)v;
        _Float16 l = (_Float16)(v - (float)h);
        Wh[t * 32 + q] = f16bits(h);
        Wl[t * 32 + q] = f16bits(l);
    }
}

// =====================================================================
// Conv-A: MFMA im2col conv, emits resp = sum_c relu(v) ONLY (no stores
// of the feature map). Grid dim3(256 tiles, 4 imgs).
// =====================================================================
__global__ __launch_bounds__(256) void convA_kernel(
        const float* __restrict__ xA,
        const ushort_t* __restrict__ Wh, const ushort_t* __restrict__ Wl,
        const float* __restrict__ bias, float* __restrict__ resp)
{
    __shared__ float    pS[CIN][3][132];
    __shared__ ushort_t Ah[64][40];
    __shared__ ushort_t Al[64][40];
    __shared__ float    redS[4][64];

    int tile = blockIdx.x;
    int b    = blockIdx.y;
    int oh   = tile >> 1;
    int ow0  = (tile & 1) << 6;
    const float* x = xA + (size_t)b * CIN * HIN * HIN;
    int tid = threadIdx.x;

    for (int i = tid; i < CIN * 3 * 129; i += 256) {
        int ci = i / (3 * 129);
        int r2 = i % (3 * 129);
        int kh = r2 / 129, c = r2 % 129;
        int gr = 2 * oh - 1 + kh, gc = 2 * ow0 - 1 + c;
        float v = 0.f;
        if (gr >= 0 && gr < HIN && gc >= 0 && gc < HIN)
            v = x[(size_t)ci * HIN * HIN + (size_t)gr * HIN + gc];
        pS[ci][kh][c] = v;
    }
    __syncthreads();

    {
        int n = tid >> 2, qg = tid & 3;
        unsigned uh[4], ul[4];
        #pragma unroll
        for (int e2 = 0; e2 < 4; ++e2) {
            ushort_t hh[2], ll[2];
            #pragma unroll
            for (int s = 0; s < 2; ++s) {
                int q = qg * 8 + e2 * 2 + s;
                float v = 0.f;
                if (q < 27) {
                    int ci = q / 9, r = (q % 9) / 3, kw = q % 3;
                    v = pS[ci][r][2 * n + kw];
                }
                _Float16 h = (_Float16)v;
                _Float16 l = (_Float16)(v - (float)h);
                hh[s] = f16bits(h); ll[s] = f16bits(l);
            }
            uh[e2] = (unsigned)hh[0] | ((unsigned)hh[1] << 16);
            ul[e2] = (unsigned)ll[0] | ((unsigned)ll[1] << 16);
        }
        *(uint4*)&Ah[n][qg * 8] = *(uint4*)uh;
        *(uint4*)&Al[n][qg * 8] = *(uint4*)ul;
    }
    __syncthreads();

    int lane = tid & 63, w = tid >> 6;
    int la = lane & 15, lg = lane >> 4;
    int wbase = w * 64;

    float bj[4];
    #pragma unroll
    for (int j = 0; j < 4; ++j) bj[j] = bias[wbase + j * 16 + la];

    f16x8 ah[4], al[4], bh[4], bl[4];
    #pragma unroll
    for (int i = 0; i < 4; ++i) {
        ah[i] = *(const f16x8*)&Ah[i * 16 + la][lg * 8];
        al[i] = *(const f16x8*)&Al[i * 16 + la][lg * 8];
    }
    #pragma unroll
    for (int j = 0; j < 4; ++j) {
        int co = wbase + j * 16 + la;
        bh[j] = *(const f16x8*)&Wh[co * 32 + lg * 8];
        bl[j] = *(const f16x8*)&Wl[co * 32 + lg * 8];
    }

    f32x4 acc[4][4];
    #pragma unroll
    for (int i = 0; i < 4; ++i)
        #pragma unroll
        for (int j = 0; j < 4; ++j) acc[i][j] = (f32x4)0.f;

    #pragma unroll
    for (int i = 0; i < 4; ++i)
        #pragma unroll
        for (int j = 0; j < 4; ++j) {
            acc[i][j] = __builtin_amdgcn_mfma_f32_16x16x32_f16(ah[i], bh[j], acc[i][j], 0, 0, 0);
            acc[i][j] = __builtin_amdgcn_mfma_f32_16x16x32_f16(al[i], bh[j], acc[i][j], 0, 0, 0);
            acc[i][j] = __builtin_amdgcn_mfma_f32_16x16x32_f16(ah[i], bl[j], acc[i][j], 0, 0, 0);
        }

    float s[4][4];
    #pragma unroll
    for (int i = 0; i < 4; ++i)
        #pragma unroll
        for (int r = 0; r < 4; ++r) s[i][r] = 0.f;

    #pragma unroll
    for (int i = 0; i < 4; ++i)
        #pragma unroll
        for (int j = 0; j < 4; ++j)
            #pragma unroll
            for (int r = 0; r < 4; ++r)
                s[i][r] += fmaxf(acc[i][j][r] + bj[j], 0.f);

    #pragma unroll
    for (int i = 0; i < 4; ++i)
        #pragma unroll
        for (int r = 0; r < 4; ++r) {
            float v = s[i][r];
            v += __shfl_xor(v, 1, 64);
            v += __shfl_xor(v, 2, 64);
            v += __shfl_xor(v, 4, 64);
            v += __shfl_xor(v, 8, 64);
            s[i][r] = v;
        }
    if (la == 0) {
        #pragma unroll
        for (int i = 0; i < 4; ++i)
            #pragma unroll
            for (int r = 0; r < 4; ++r)
                redS[w][i * 16 + lg * 4 + r] = s[i][r];
    }
    __syncthreads();
    if (tid < 64) {
        float tot = redS[0][tid] + redS[1][tid] + redS[2][tid] + redS[3][tid];
        resp[(size_t)b * NF + oh * HF + ow0 + tid] = tot;
    }
}

// =====================================================================
// Fused select: pool argmax (wave 0) + descriptor conv-recompute (fp32 exact).
// =====================================================================
__global__ __launch_bounds__(256) void select_kernel(
        const float* __restrict__ resp,
        const float* __restrict__ xA, const float* __restrict__ W,
        const float* __restrict__ bias,
        int* __restrict__ idxA,
        ushort_t* __restrict__ desc_h, ushort_t* __restrict__ desc_l,
        float* __restrict__ normA)
{
    __shared__ float patch[27];
    __shared__ float red[4];
    __shared__ int   sidx;

    int bk = blockIdx.x;              // b*KK + k
    int b = bk >> 8, kIdx = bk & 255;
    int t = threadIdx.x;

    if (t < 64) {
        int kr = kIdx >> 4, kc = kIdx & 15;
        int lr = t >> 3, lc = t & 7;
        int row = kr * 8 + lr, col = kc * 8 + lc;
        float bv = resp[(size_t)b * NF + (size_t)row * HF + col];
        int best = t;
        for (int off = 32; off > 0; off >>= 1) {
            float ov = __shfl_down(bv, off, 64);
            int   oi = __shfl_down(best, off, 64);
            if (ov > bv || (ov == bv && oi < best)) { bv = ov; best = oi; }
        }
        if (t == 0) {
            int r = kr * 8 + (best >> 3), c = kc * 8 + (best & 7);
            int idx = r * HF + c;
            idxA[bk] = idx;
            sidx = idx;
        }
    }
    __syncthreads();
    int idx = sidx;
    int oh = idx >> 7, ow = idx & 127;

    if (t < 27) {
        int ci = t / 9, kh = (t % 9) / 3, kw = t % 3;
        int ir = oh * 2 - 1 + kh, ic = ow * 2 - 1 + kw;
        float v = 0.f;
        if (ir >= 0 && ir < HIN && ic >= 0 && ic < HIN)
            v = xA[((size_t)b * CIN + ci) * HIN * HIN + (size_t)ir * HIN + ic];
        patch[t] = v;
    }
    __syncthreads();

    float v = bias[t];
    const float* w = &W[t * 27];
    #pragma unroll
    for (int q = 0; q < 27; ++q) v = fmaf(patch[q], w[q], v);
    v = fmaxf(v, 0.f);

    _Float16 h = (_Float16)v;
    _Float16 l = (_Float16)(v - (float)h);
    desc_h[(size_t)bk * COUT + t] = f16bits(h);
    desc_l[(size_t)bk * COUT + t] = f16bits(l);

    float s = v * v;
    for (int off = 32; off > 0; off >>= 1) s += __shfl_down(s, off, 64);
    if ((t & 63) == 0) red[t >> 6] = s;
    __syncthreads();
    if (t == 0) normA[bk] = red[0] + red[1] + red[2] + red[3];
}

// =====================================================================
// FUSED conv-B + kNN: per block = 64 B-pixels (one tile) x all 256 k.
// Conv-B computes the 64x256 feature tile in accumulators, splits to
// f16 h/l planes in LDS (never touches HBM), computes normB in-kernel,
// then runs the barrier-free 3-pass MFMA kNN against desc (global, L2-hot).
// LDS: conv region (pS+Ah+Al, 15KB) aliased with fH/fL (66KB) -> 2 blk/CU.
// =====================================================================
__global__ __launch_bounds__(256) void fused_kernel(
        const float* __restrict__ xB,
        const ushort_t* __restrict__ Wh, const ushort_t* __restrict__ Wl,
        const float* __restrict__ bias,
        const ushort_t* __restrict__ desc_h, const ushort_t* __restrict__ desc_l,
        const float* __restrict__ normA,
        unsigned long long* __restrict__ scratch)
{
    __shared__ __align__(16) char smem[2 * 64 * FST * 2];   // 67584 B
    __shared__ float redS[4][64];
    __shared__ float nAS[KK];
    __shared__ float nBS[64];

    float*    pSp = (float*)smem;                            // [3][3][132] = 4752B
    ushort_t* AhP = (ushort_t*)(smem + 4752);                // [64][40] = 5120B
    ushort_t* AlP = (ushort_t*)(smem + 4752 + 5120);         // [64][40]
    ushort_t* fH  = (ushort_t*)smem;                         // [64][FST]
    ushort_t* fL  = (ushort_t*)(smem + 64 * FST * 2);        // [64][FST]

    int tile = blockIdx.x;           // 0..255 (n-tile)
    int b    = blockIdx.y;
    int oh   = tile >> 1;
    int ow0  = (tile & 1) << 6;
    const float* x = xB + (size_t)b * CIN * HIN * HIN;
    int tid = threadIdx.x;

    nAS[tid] = normA[b * KK + tid];

    // ---- stage input rows ----
    for (int i = tid; i < CIN * 3 * 129; i += 256) {
        int ci = i / (3 * 129);
        int r2 = i % (3 * 129);
        int kh = r2 / 129, c = r2 % 129;
        int gr = 2 * oh - 1 + kh, gc = 2 * ow0 - 1 + c;
        float v = 0.f;
        if (gr >= 0 && gr < HIN && gc >= 0 && gc < HIN)
            v = x[(size_t)ci * HIN * HIN + (size_t)gr * HIN + gc];
        pSp[ci * 3 * 132 + kh * 132 + c] = v;
    }
    __syncthreads();

    // ---- im2col ----
    {
        int n = tid >> 2, qg = tid & 3;
        unsigned uh[4], ul[4];
        #pragma unroll
        for (int e2 = 0; e2 < 4; ++e2) {
            ushort_t hh[2], ll[2];
            #pragma unroll
            for (int s = 0; s < 2; ++s) {
                int q = qg * 8 + e2 * 2 + s;
                float v = 0.f;
                if (q < 27) {
                    int ci = q / 9, r = (q % 9) / 3, kw = q % 3;
                    v = pSp[ci * 3 * 132 + r * 132 + 2 * n + kw];
                }
                _Float16 h = (_Float16)v;
                _Float16 l = (_Float16)(v - (float)h);
                hh[s] = f16bits(h); ll[s] = f16bits(l);
            }
            uh[e2] = (unsigned)hh[0] | ((unsigned)hh[1] << 16);
            ul[e2] = (unsigned)ll[0] | ((unsigned)ll[1] << 16);
        }
        *(uint4*)&AhP[n * 40 + qg * 8] = *(uint4*)uh;
        *(uint4*)&AlP[n * 40 + qg * 8] = *(uint4*)ul;
    }
    __syncthreads();

    int lane = tid & 63, w = tid >> 6;
    int la = lane & 15, lg = lane >> 4;
    int wbase = w * 64;

    float bj[4];
    #pragma unroll
    for (int j = 0; j < 4; ++j) bj[j] = bias[wbase + j * 16 + la];

    // ---- conv MFMA ----
    f16x8 cah[4], cal[4], cbh[4], cbl[4];
    #pragma unroll
    for (int i = 0; i < 4; ++i) {
        cah[i] = *(const f16x8*)&AhP[(i * 16 + la) * 40 + lg * 8];
        cal[i] = *(const f16x8*)&AlP[(i * 16 + la) * 40 + lg * 8];
    }
    #pragma unroll
    for (int j = 0; j < 4; ++j) {
        int co = wbase + j * 16 + la;
        cbh[j] = *(const f16x8*)&Wh[co * 32 + lg * 8];
        cbl[j] = *(const f16x8*)&Wl[co * 32 + lg * 8];
    }

    f32x4 cacc[4][4];
    #pragma unroll
    for (int i = 0; i < 4; ++i)
        #pragma unroll
        for (int j = 0; j < 4; ++j) cacc[i][j] = (f32x4)0.f;

    #pragma unroll
    for (int i = 0; i < 4; ++i)
        #pragma unroll
        for (int j = 0; j < 4; ++j) {
            cacc[i][j] = __builtin_amdgcn_mfma_f32_16x16x32_f16(cah[i], cbh[j], cacc[i][j], 0, 0, 0);
            cacc[i][j] = __builtin_amdgcn_mfma_f32_16x16x32_f16(cal[i], cbh[j], cacc[i][j], 0, 0, 0);
            cacc[i][j] = __builtin_amdgcn_mfma_f32_16x16x32_f16(cah[i], cbl[j], cacc[i][j], 0, 0, 0);
        }

    __syncthreads();   // all waves done reading Ah/Al (aliased with fH/fL)

    // ---- epilogue: relu, f16-split into LDS planes, sumsq ----
    float s[4][4];
    #pragma unroll
    for (int i = 0; i < 4; ++i)
        #pragma unroll
        for (int r = 0; r < 4; ++r) s[i][r] = 0.f;

    #pragma unroll
    for (int i = 0; i < 4; ++i) {
        #pragma unroll
        for (int j = 0; j < 4; ++j) {
            int co = wbase + j * 16 + la;
            #pragma unroll
            for (int r = 0; r < 4; ++r) {
                float v = fmaxf(cacc[i][j][r] + bj[j], 0.f);
                _Float16 h = (_Float16)v;
                _Float16 l = (_Float16)(v - (float)h);
                int pix = i * 16 + lg * 4 + r;
                fH[pix * FST + co] = f16bits(h);
                fL[pix * FST + co] = f16bits(l);
                s[i][r] = fmaf(v, v, s[i][r]);
            }
        }
    }
    #pragma unroll
    for (int i = 0; i < 4; ++i)
        #pragma unroll
        for (int r = 0; r < 4; ++r) {
            float v = s[i][r];
            v += __shfl_xor(v, 1, 64);
            v += __shfl_xor(v, 2, 64);
            v += __shfl_xor(v, 4, 64);
            v += __shfl_xor(v, 8, 64);
            s[i][r] = v;
        }
    if (la == 0) {
        #pragma unroll
        for (int i = 0; i < 4; ++i)
            #pragma unroll
            for (int r = 0; r < 4; ++r)
                redS[w][i * 16 + lg * 4 + r] = s[i][r];
    }
    __syncthreads();
    if (tid < 64) nBS[tid] = redS[0][tid] + redS[1][tid] + redS[2][tid] + redS[3][tid];
    __syncthreads();

    // ---- kNN: barrier-free 3-pass MFMA over c-chunks ----
    const ushort_t* dh = desc_h + (size_t)b * KK * COUT;
    const ushort_t* dl = desc_l + (size_t)b * KK * COUT;
    int kw0 = wbase;

    f32x4 acc[4][4];
    #pragma unroll
    for (int i = 0; i < 4; ++i)
        #pragma unroll
        for (int j = 0; j < 4; ++j) acc[i][j] = (f32x4)0.f;

    #pragma unroll 2
    for (int cc = 0; cc < COUT; cc += 32) {
        f16x8 bh[4], bl[4];
        #pragma unroll
        for (int j = 0; j < 4; ++j) {
            size_t off = (size_t)(kw0 + j * 16 + la) * COUT + cc + lg * 8;
            bh[j] = *(const f16x8*)&dh[off];
            bl[j] = *(const f16x8*)&dl[off];
        }
        f16x8 ah2[4], al2[4];
        #pragma unroll
        for (int i = 0; i < 4; ++i) {
            ah2[i] = *(const f16x8*)&fH[(i * 16 + la) * FST + cc + lg * 8];
            al2[i] = *(const f16x8*)&fL[(i * 16 + la) * FST + cc + lg * 8];
        }
        __builtin_amdgcn_s_setprio(1);
        #pragma unroll
        for (int i = 0; i < 4; ++i)
            #pragma unroll
            for (int j = 0; j < 4; ++j) {
                acc[i][j] = __builtin_amdgcn_mfma_f32_16x16x32_f16(ah2[i], bh[j], acc[i][j], 0, 0, 0);
                acc[i][j] = __builtin_amdgcn_mfma_f32_16x16x32_f16(al2[i], bh[j], acc[i][j], 0, 0, 0);
                acc[i][j] = __builtin_amdgcn_mfma_f32_16x16x32_f16(ah2[i], bl[j], acc[i][j], 0, 0, 0);
            }
        __builtin_amdgcn_s_setprio(0);
    }

    // ---- epilogue: dist + per-k argmin ----
    float nBv[4][4];
    #pragma unroll
    for (int i = 0; i < 4; ++i) {
        f32x4 t4 = *(const f32x4*)&nBS[i * 16 + lg * 4];
        nBv[i][0] = t4[0]; nBv[i][1] = t4[1]; nBv[i][2] = t4[2]; nBv[i][3] = t4[3];
    }
    int n0 = tile * 64;
    #pragma unroll
    for (int j = 0; j < 4; ++j) {
        int kl = kw0 + j * 16 + la;
        float nAv = nAS[kl];
        unsigned long long best = ~0ull;
        #pragma unroll
        for (int i = 0; i < 4; ++i)
            #pragma unroll
            for (int r = 0; r < 4; ++r) {
                int n = n0 + i * 16 + lg * 4 + r;
                float d = fmaf(-2.f, acc[i][j][r], nAv) + nBv[i][r];
                unsigned u = __float_as_uint(d);
                u = (u & 0x80000000u) ? ~u : (u | 0x80000000u);
                unsigned long long key = ((unsigned long long)u << 32) | (unsigned)n;
                best = u64min(best, key);
            }
        best = u64min(best, shfl_xor_u64(best, 16));
        best = u64min(best, shfl_xor_u64(best, 32));
        if (lg == 0)
            scratch[(size_t)(b * KK + kl) * 256 + tile] = best;
    }
}

// =====================================================================
// Final argmin reduce over the 256 tiles -> minN[b*KK + k]
// =====================================================================
__global__ __launch_bounds__(64) void reduce_kernel(
        const unsigned long long* __restrict__ scratch, int* __restrict__ minN)
{
    int bk = blockIdx.x;              // b*KK + k
    int t = threadIdx.x;
    const unsigned long long* s = scratch + (size_t)bk * 256;
    unsigned long long best = s[t];
    best = u64min(best, s[t + 64]);
    best = u64min(best, s[t + 128]);
    best = u64min(best, s[t + 192]);
    for (int off = 32; off > 0; off >>= 1)
        best = u64min(best, shfl_down_u64(best, off));
    if (t == 0) minN[bk] = (int)(best & 0xffffffffULL);
}

// =====================================================================
// Two tiny MLPs: x(256) -> 128 relu -> 1. block per (b, which), 128 threads.
// =====================================================================
__global__ __launch_bounds__(128) void mlp_kernel(
        const int* __restrict__ idxA, const int* __restrict__ minN,
        const float* __restrict__ W1r, const float* __restrict__ b1r,
        const float* __restrict__ W2r, const float* __restrict__ b2r,
        const float* __restrict__ W1c, const float* __restrict__ b1c,
        const float* __restrict__ W2c, const float* __restrict__ b2c,
        float* __restrict__ out)
{
    __shared__ float xS[KK];
    __shared__ float red[2];
    int blk = blockIdx.x;            // b*2 + which
    int b = blk >> 1, which = blk & 1;
    int t = threadIdx.x;             // 0..127

    for (int k = t; k < KK; k += 128) {
        int ia = idxA[b * KK + k];
        int nn = minN[b * KK + k];
        int rowA = ia >> 7, colA = ia & 127;
        int rowB = nn >> 7, colB = nn & 127;
        xS[k] = (which == 0) ? (float)(rowB - rowA) : (float)(colA - colB);
    }
    __syncthreads();

    const float* W1 = which ? W1c : W1r;
    const float* b1 = which ? b1c : b1r;
    const float* W2 = which ? W2c : W2r;
    const float* b2 = which ? b2c : b2r;

    float h = b1[t];
    for (int k = 0; k < KK; ++k) h = fmaf(xS[k], W1[k * HID + t], h);
    h = fmaxf(h, 0.f);
    float pv = h * W2[t];
    for (int off = 32; off > 0; off >>= 1) pv += __shfl_down(pv, off, 64);
    if ((t & 63) == 0) red[t >> 6] = pv;
    __syncthreads();
    if (t == 0) out[b * 2 + which] = red[0] + red[1] + b2[0];
}

// =====================================================================
extern "C" void kernel_launch(void* const* d_in, const int* in_sizes, int n_in,
                              void* d_out, int out_size, void* d_ws, size_t ws_size,
                              hipStream_t stream)
{
    const float* xA  = (const float*)d_in[0];
    const float* xB  = (const float*)d_in[1];
    const float* Wc  = (const float*)d_in[2];
    const float* bc  = (const float*)d_in[3];
    const float* W1r = (const float*)d_in[4];
    const float* b1r = (const float*)d_in[5];
    const float* W2r = (const float*)d_in[6];
    const float* b2r = (const float*)d_in[7];
    const float* W1c = (const float*)d_in[8];
    const float* b1c = (const float*)d_in[9];
    const float* W2c = (const float*)d_in[10];
    const float* b2c = (const float*)d_in[11];
    float* out = (float*)d_out;

    char* ws = (char*)d_ws;
    unsigned long long* scratch = (unsigned long long*)ws; ws += (size_t)NB * KK * 256 * 8;
    int*   idxA   = (int*)ws;      ws += (size_t)NB * KK * 4;
    int*   minN   = (int*)ws;      ws += (size_t)NB * KK * 4;
    float* normA  = (float*)ws;    ws += (size_t)NB * KK * 4;
    float* resp   = (float*)ws;    ws += (size_t)NB * NF * 4;
    ushort_t* desc_h = (ushort_t*)ws; ws += (size_t)NB * KK * COUT * 2;
    ushort_t* desc_l = (ushort_t*)ws; ws += (size_t)NB * KK * COUT * 2;
    ushort_t* Wh  = (ushort_t*)ws; ws += (size_t)COUT * 32 * 2;
    ushort_t* Wl  = (ushort_t*)ws; ws += (size_t)COUT * 32 * 2;

    prep_kernel  <<<1, 256, 0, stream>>>(Wc, Wh, Wl);
    convA_kernel <<<dim3(256, NB), 256, 0, stream>>>(xA, Wh, Wl, bc, resp);
    select_kernel<<<NB * KK, 256, 0, stream>>>(resp, xA, Wc, bc, idxA, desc_h, desc_l, normA);
    fused_kernel <<<dim3(256, NB), 256, 0, stream>>>(xB, Wh, Wl, bc, desc_h, desc_l,
                                                     normA, scratch);
    reduce_kernel<<<NB * KK, 64, 0, stream>>>(scratch, minN);
    mlp_kernel   <<<8, 128, 0, stream>>>(idxA, minN,
                                         W1r, b1r, W2r, b2r,
                                         W1c, b1c, W2c, b2c, out);
}

// Round 9
// 69.061 us; speedup vs baseline: 1.7100x; 1.1664x over previous
//
#include <hip/hip_runtime.h>
#include <stdint.h>

// ---- problem constants ----
constexpr int NB   = 4;      // batch
constexpr int CIN  = 3;
constexpr int HIN  = 256;
constexpr int COUT = 256;
constexpr int HF   = 128;              // feature H=W after stride-2 conv
constexpr int NF   = HF * HF;          // 16384
constexpr int KADM = 16;
constexpr int KK   = KADM * KADM;      // 256 descriptors
constexpr int HID  = 128;              // MLP hidden
constexpr int DFB  = 65536;            // desc-fragment u16s per batch

typedef unsigned short ushort_t;
typedef __attribute__((ext_vector_type(8))) _Float16 f16x8;
typedef __attribute__((ext_vector_type(4))) float    f32x4;

__device__ inline unsigned long long shfl_xor_u64(unsigned long long v, int m) {
    unsigned lo = __shfl_xor((unsigned)v, m, 64);
    unsigned hi = __shfl_xor((unsigned)(v >> 32), m, 64);
    return ((unsigned long long)hi << 32) | lo;
}
__device__ inline unsigned long long shfl_down_u64(unsigned long long v, int off) {
    unsigned lo = __shfl_down((unsigned)v, off, 64);
    unsigned hi = __shfl_down((unsigned)(v >> 32), off, 64);
    return ((unsigned long long)hi << 32) | lo;
}
__device__ inline unsigned long long u64min(unsigned long long a, unsigned long long b) {
    return a < b ? a : b;
}
__device__ inline ushort_t f16bits(_Float16 h) { return __builtin_bit_cast(ushort_t, h); }

// LDS swizzle for the [64][256] f16 feature planes: XOR the 8-f16 chunk
// index with pix&7 -> row-major reads (lanes = rows) land on distinct banks.
__device__ inline int swz(int pix, int c) {
    return pix * 256 + ((((c >> 3) ^ (pix & 7)) << 3) | (c & 7));
}

// desc fragment address: [w][chunk][j][lane][8]
__device__ inline int dfoff(int w, int chunk, int j, int lane) {
    return (((w * 8 + chunk) * 4 + j) * 64 + lane) * 8;
}

// =====================================================================
// Prep: split conv weights into f16 hi/lo, K padded 27->32, stored in
// MFMA B-fragment order: [w][j][lane=lg*16+la][8] (co = w*64+j*16+la).
// =====================================================================
__global__ __launch_bounds__(256) void prep_kernel(
        const float* __restrict__ W, ushort_t* __restrict__ WFh, ushort_t* __restrict__ WFl)
{
    int co = threadIdx.x;
    int w = co >> 6, j = (co >> 4) & 3, la = co & 15;
    #pragma unroll
    for (int q = 0; q < 32; ++q) {
        float v = (q < 27) ? W[co * 27 + q] : 0.f;
        _Float16 h = (_Float16)v;
        _Float16 l = (_Float16)(v - (float)h);
        int lg = q >> 3, e = q & 7;
        int off = ((w * 4 + j) * 64 + lg * 16 + la) * 8 + e;
        WFh[off] = f16bits(h);
        WFl[off] = f16bits(l);
    }
}

// =====================================================================
// Conv-A: MFMA im2col conv, emits resp = sum_c relu(v) only.
// =====================================================================
__global__ __launch_bounds__(256) void convA_kernel(
        const float* __restrict__ xA,
        const ushort_t* __restrict__ WFh, const ushort_t* __restrict__ WFl,
        const float* __restrict__ bias, float* __restrict__ resp)
{
    __shared__ float    pS[CIN][3][132];
    __shared__ ushort_t Ah[64][40];
    __shared__ ushort_t Al[64][40];
    __shared__ float    redS[4][64];

    int tile = blockIdx.x;
    int b    = blockIdx.y;
    int oh   = tile >> 1;
    int ow0  = (tile & 1) << 6;
    const float* x = xA + (size_t)b * CIN * HIN * HIN;
    int tid = threadIdx.x;

    for (int i = tid; i < CIN * 3 * 129; i += 256) {
        int ci = i / (3 * 129);
        int r2 = i % (3 * 129);
        int kh = r2 / 129, c = r2 % 129;
        int gr = 2 * oh - 1 + kh, gc = 2 * ow0 - 1 + c;
        float v = 0.f;
        if (gr >= 0 && gr < HIN && gc >= 0 && gc < HIN)
            v = x[(size_t)ci * HIN * HIN + (size_t)gr * HIN + gc];
        pS[ci][kh][c] = v;
    }
    __syncthreads();

    {
        int n = tid >> 2, qg = tid & 3;
        unsigned uh[4], ul[4];
        #pragma unroll
        for (int e2 = 0; e2 < 4; ++e2) {
            ushort_t hh[2], ll[2];
            #pragma unroll
            for (int s = 0; s < 2; ++s) {
                int q = qg * 8 + e2 * 2 + s;
                float v = 0.f;
                if (q < 27) {
                    int ci = q / 9, r = (q % 9) / 3, kw = q % 3;
                    v = pS[ci][r][2 * n + kw];
                }
                _Float16 h = (_Float16)v;
                _Float16 l = (_Float16)(v - (float)h);
                hh[s] = f16bits(h); ll[s] = f16bits(l);
            }
            uh[e2] = (unsigned)hh[0] | ((unsigned)hh[1] << 16);
            ul[e2] = (unsigned)ll[0] | ((unsigned)ll[1] << 16);
        }
        *(uint4*)&Ah[n][qg * 8] = *(uint4*)uh;
        *(uint4*)&Al[n][qg * 8] = *(uint4*)ul;
    }
    __syncthreads();

    int lane = tid & 63, w = tid >> 6;
    int la = lane & 15, lg = lane >> 4;
    int wbase = w * 64;

    float bj[4];
    #pragma unroll
    for (int j = 0; j < 4; ++j) bj[j] = bias[wbase + j * 16 + la];

    f16x8 ah[4], al[4], bh[4], bl[4];
    #pragma unroll
    for (int i = 0; i < 4; ++i) {
        ah[i] = *(const f16x8*)&Ah[i * 16 + la][lg * 8];
        al[i] = *(const f16x8*)&Al[i * 16 + la][lg * 8];
    }
    #pragma unroll
    for (int j = 0; j < 4; ++j) {
        int off = ((w * 4 + j) * 64 + lane) * 8;
        bh[j] = *(const f16x8*)&WFh[off];
        bl[j] = *(const f16x8*)&WFl[off];
    }

    f32x4 acc[4][4];
    #pragma unroll
    for (int i = 0; i < 4; ++i)
        #pragma unroll
        for (int j = 0; j < 4; ++j) acc[i][j] = (f32x4)0.f;

    #pragma unroll
    for (int i = 0; i < 4; ++i)
        #pragma unroll
        for (int j = 0; j < 4; ++j) {
            acc[i][j] = __builtin_amdgcn_mfma_f32_16x16x32_f16(ah[i], bh[j], acc[i][j], 0, 0, 0);
            acc[i][j] = __builtin_amdgcn_mfma_f32_16x16x32_f16(al[i], bh[j], acc[i][j], 0, 0, 0);
            acc[i][j] = __builtin_amdgcn_mfma_f32_16x16x32_f16(ah[i], bl[j], acc[i][j], 0, 0, 0);
        }

    float s[4][4];
    #pragma unroll
    for (int i = 0; i < 4; ++i)
        #pragma unroll
        for (int r = 0; r < 4; ++r) s[i][r] = 0.f;

    #pragma unroll
    for (int i = 0; i < 4; ++i)
        #pragma unroll
        for (int j = 0; j < 4; ++j)
            #pragma unroll
            for (int r = 0; r < 4; ++r)
                s[i][r] += fmaxf(acc[i][j][r] + bj[j], 0.f);

    #pragma unroll
    for (int i = 0; i < 4; ++i)
        #pragma unroll
        for (int r = 0; r < 4; ++r) {
            float v = s[i][r];
            v += __shfl_xor(v, 1, 64);
            v += __shfl_xor(v, 2, 64);
            v += __shfl_xor(v, 4, 64);
            v += __shfl_xor(v, 8, 64);
            s[i][r] = v;
        }
    if (la == 0) {
        #pragma unroll
        for (int i = 0; i < 4; ++i)
            #pragma unroll
            for (int r = 0; r < 4; ++r)
                redS[w][i * 16 + lg * 4 + r] = s[i][r];
    }
    __syncthreads();
    if (tid < 64) {
        float tot = redS[0][tid] + redS[1][tid] + redS[2][tid] + redS[3][tid];
        resp[(size_t)b * NF + oh * HF + ow0 + tid] = tot;
    }
}

// =====================================================================
// Fused select: pool argmax (wave 0) + descriptor conv-recompute (fp32).
// Writes desc in MFMA B-fragment order: dFh/dFl[b][w][chunk][j][lane][8].
// =====================================================================
__global__ __launch_bounds__(256) void select_kernel(
        const float* __restrict__ resp,
        const float* __restrict__ xA, const float* __restrict__ W,
        const float* __restrict__ bias,
        int* __restrict__ idxA,
        ushort_t* __restrict__ dFh, ushort_t* __restrict__ dFl,
        float* __restrict__ normA)
{
    __shared__ float patch[27];
    __shared__ float red[4];
    __shared__ int   sidx;

    int bk = blockIdx.x;              // b*KK + k
    int b = bk >> 8, k = bk & 255;
    int t = threadIdx.x;              // channel c

    if (t < 64) {
        int kr = k >> 4, kc = k & 15;
        int lr = t >> 3, lc = t & 7;
        int row = kr * 8 + lr, col = kc * 8 + lc;
        float bv = resp[(size_t)b * NF + (size_t)row * HF + col];
        int best = t;
        for (int off = 32; off > 0; off >>= 1) {
            float ov = __shfl_down(bv, off, 64);
            int   oi = __shfl_down(best, off, 64);
            if (ov > bv || (ov == bv && oi < best)) { bv = ov; best = oi; }
        }
        if (t == 0) {
            int r = kr * 8 + (best >> 3), c = kc * 8 + (best & 7);
            int idx = r * HF + c;
            idxA[bk] = idx;
            sidx = idx;
        }
    }
    __syncthreads();
    int idx = sidx;
    int oh = idx >> 7, ow = idx & 127;

    if (t < 27) {
        int ci = t / 9, kh = (t % 9) / 3, kw = t % 3;
        int ir = oh * 2 - 1 + kh, ic = ow * 2 - 1 + kw;
        float v = 0.f;
        if (ir >= 0 && ir < HIN && ic >= 0 && ic < HIN)
            v = xA[((size_t)b * CIN + ci) * HIN * HIN + (size_t)ir * HIN + ic];
        patch[t] = v;
    }
    __syncthreads();

    float v = bias[t];
    const float* w = &W[t * 27];
    #pragma unroll
    for (int q = 0; q < 27; ++q) v = fmaf(patch[q], w[q], v);
    v = fmaxf(v, 0.f);

    _Float16 h = (_Float16)v;
    _Float16 l = (_Float16)(v - (float)h);
    // fragment position: w=k>>6, j=(k>>4)&3, la=k&15; chunk=t>>5, lg=(t>>3)&3, e=t&7
    {
        int wq = k >> 6, j = (k >> 4) & 3, la = k & 15;
        int chunk = t >> 5, lg = (t >> 3) & 3, e = t & 7;
        int off = b * DFB + dfoff(wq, chunk, j, lg * 16 + la) + e;
        dFh[off] = f16bits(h);
        dFl[off] = f16bits(l);
    }

    float s = v * v;
    for (int off = 32; off > 0; off >>= 1) s += __shfl_down(s, off, 64);
    if ((t & 63) == 0) red[t >> 6] = s;
    __syncthreads();
    if (t == 0) normA[bk] = red[0] + red[1] + red[2] + red[3];
}

// ---- fused-kernel helpers ----
__device__ inline void load_desc(const ushort_t* __restrict__ dFh,
                                 const ushort_t* __restrict__ dFl,
                                 int w, int chunk, int lane,
                                 f16x8* bh, f16x8* bl)
{
    #pragma unroll
    for (int j = 0; j < 4; ++j) {
        int off = dfoff(w, chunk, j, lane);
        bh[j] = *(const f16x8*)&dFh[off];
        bl[j] = *(const f16x8*)&dFl[off];
    }
}

__device__ inline void knn_chunk(const ushort_t* __restrict__ fH,
                                 const ushort_t* __restrict__ fL,
                                 int la, int lg, int cc,
                                 const f16x8* bh, const f16x8* bl,
                                 f32x4 (&acc)[4][4])
{
    #pragma unroll
    for (int i = 0; i < 4; ++i) {
        f16x8 ah = *(const f16x8*)&fH[swz(i * 16 + la, cc + lg * 8)];
        f16x8 al = *(const f16x8*)&fL[swz(i * 16 + la, cc + lg * 8)];
        __builtin_amdgcn_s_setprio(1);
        #pragma unroll
        for (int j = 0; j < 4; ++j) {
            acc[i][j] = __builtin_amdgcn_mfma_f32_16x16x32_f16(ah, bh[j], acc[i][j], 0, 0, 0);
            acc[i][j] = __builtin_amdgcn_mfma_f32_16x16x32_f16(al, bh[j], acc[i][j], 0, 0, 0);
            acc[i][j] = __builtin_amdgcn_mfma_f32_16x16x32_f16(ah, bl[j], acc[i][j], 0, 0, 0);
        }
        __builtin_amdgcn_s_setprio(0);
    }
}

// =====================================================================
// FUSED conv-B + kNN.
// =====================================================================
__global__ __launch_bounds__(256) void fused_kernel(
        const float* __restrict__ xB,
        const ushort_t* __restrict__ WFh, const ushort_t* __restrict__ WFl,
        const float* __restrict__ bias,
        const ushort_t* __restrict__ dFhg, const ushort_t* __restrict__ dFlg,
        const float* __restrict__ normA,
        unsigned long long* __restrict__ scratch)
{
    __shared__ __align__(16) char smem[2 * 64 * 256 * 2];   // 65536 B
    __shared__ float redS[4][64];
    __shared__ float nAS[KK];
    __shared__ float nBS[64];

    float*    pSp = (float*)smem;                            // [3][3][132] = 4752B
    ushort_t* AhP = (ushort_t*)(smem + 4752);                // [64][40]
    ushort_t* AlP = (ushort_t*)(smem + 4752 + 5120);         // [64][40]
    ushort_t* fH  = (ushort_t*)smem;                         // [64][256] swizzled
    ushort_t* fL  = (ushort_t*)(smem + 64 * 256 * 2);        // [64][256] swizzled

    int tile = blockIdx.x;           // 0..255 (n-tile)
    int b    = blockIdx.y;
    int oh   = tile >> 1;
    int ow0  = (tile & 1) << 6;
    const float* x = xB + (size_t)b * CIN * HIN * HIN;
    int tid = threadIdx.x;

    nAS[tid] = normA[b * KK + tid];

    for (int i = tid; i < CIN * 3 * 129; i += 256) {
        int ci = i / (3 * 129);
        int r2 = i % (3 * 129);
        int kh = r2 / 129, c = r2 % 129;
        int gr = 2 * oh - 1 + kh, gc = 2 * ow0 - 1 + c;
        float v = 0.f;
        if (gr >= 0 && gr < HIN && gc >= 0 && gc < HIN)
            v = x[(size_t)ci * HIN * HIN + (size_t)gr * HIN + gc];
        pSp[ci * 3 * 132 + kh * 132 + c] = v;
    }
    __syncthreads();

    {
        int n = tid >> 2, qg = tid & 3;
        unsigned uh[4], ul[4];
        #pragma unroll
        for (int e2 = 0; e2 < 4; ++e2) {
            ushort_t hh[2], ll[2];
            #pragma unroll
            for (int s = 0; s < 2; ++s) {
                int q = qg * 8 + e2 * 2 + s;
                float v = 0.f;
                if (q < 27) {
                    int ci = q / 9, r = (q % 9) / 3, kw = q % 3;
                    v = pSp[ci * 3 * 132 + r * 132 + 2 * n + kw];
                }
                _Float16 h = (_Float16)v;
                _Float16 l = (_Float16)(v - (float)h);
                hh[s] = f16bits(h); ll[s] = f16bits(l);
            }
            uh[e2] = (unsigned)hh[0] | ((unsigned)hh[1] << 16);
            ul[e2] = (unsigned)ll[0] | ((unsigned)ll[1] << 16);
        }
        *(uint4*)&AhP[n * 40 + qg * 8] = *(uint4*)uh;
        *(uint4*)&AlP[n * 40 + qg * 8] = *(uint4*)ul;
    }
    __syncthreads();

    int lane = tid & 63, w = tid >> 6;
    int la = lane & 15, lg = lane >> 4;
    int wbase = w * 64;

    float bj[4];
    #pragma unroll
    for (int j = 0; j < 4; ++j) bj[j] = bias[wbase + j * 16 + la];

    // ---- conv MFMA ----
    f16x8 cah[4], cal[4], cbh[4], cbl[4];
    #pragma unroll
    for (int i = 0; i < 4; ++i) {
        cah[i] = *(const f16x8*)&AhP[(i * 16 + la) * 40 + lg * 8];
        cal[i] = *(const f16x8*)&AlP[(i * 16 + la) * 40 + lg * 8];
    }
    #pragma unroll
    for (int j = 0; j < 4; ++j) {
        int off = ((w * 4 + j) * 64 + lane) * 8;
        cbh[j] = *(const f16x8*)&WFh[off];
        cbl[j] = *(const f16x8*)&WFl[off];
    }

    f32x4 cacc[4][4];
    #pragma unroll
    for (int i = 0; i < 4; ++i)
        #pragma unroll
        for (int j = 0; j < 4; ++j) cacc[i][j] = (f32x4)0.f;

    #pragma unroll
    for (int i = 0; i < 4; ++i)
        #pragma unroll
        for (int j = 0; j < 4; ++j) {
            cacc[i][j] = __builtin_amdgcn_mfma_f32_16x16x32_f16(cah[i], cbh[j], cacc[i][j], 0, 0, 0);
            cacc[i][j] = __builtin_amdgcn_mfma_f32_16x16x32_f16(cal[i], cbh[j], cacc[i][j], 0, 0, 0);
            cacc[i][j] = __builtin_amdgcn_mfma_f32_16x16x32_f16(cah[i], cbl[j], cacc[i][j], 0, 0, 0);
        }

    __syncthreads();   // all waves done reading Ah/Al (aliased with fH/fL)

    // ---- epilogue: relu, f16-split into swizzled LDS planes, sumsq ----
    float s[4][4];
    #pragma unroll
    for (int i = 0; i < 4; ++i)
        #pragma unroll
        for (int r = 0; r < 4; ++r) s[i][r] = 0.f;

    #pragma unroll
    for (int i = 0; i < 4; ++i) {
        #pragma unroll
        for (int j = 0; j < 4; ++j) {
            int co = wbase + j * 16 + la;
            #pragma unroll
            for (int r = 0; r < 4; ++r) {
                float v = fmaxf(cacc[i][j][r] + bj[j], 0.f);
                _Float16 h = (_Float16)v;
                _Float16 l = (_Float16)(v - (float)h);
                int pix = i * 16 + lg * 4 + r;
                fH[swz(pix, co)] = f16bits(h);
                fL[swz(pix, co)] = f16bits(l);
                s[i][r] = fmaf(v, v, s[i][r]);
            }
        }
    }
    #pragma unroll
    for (int i = 0; i < 4; ++i)
        #pragma unroll
        for (int r = 0; r < 4; ++r) {
            float v = s[i][r];
            v += __shfl_xor(v, 1, 64);
            v += __shfl_xor(v, 2, 64);
            v += __shfl_xor(v, 4, 64);
            v += __shfl_xor(v, 8, 64);
            s[i][r] = v;
        }
    if (la == 0) {
        #pragma unroll
        for (int i = 0; i < 4; ++i)
            #pragma unroll
            for (int r = 0; r < 4; ++r)
                redS[w][i * 16 + lg * 4 + r] = s[i][r];
    }
    __syncthreads();
    if (tid < 64) nBS[tid] = redS[0][tid] + redS[1][tid] + redS[2][tid] + redS[3][tid];
    __syncthreads();

    // ---- kNN: 3-pass MFMA, 2-deep desc prefetch, no barriers ----
    const ushort_t* dFh = dFhg + (size_t)b * DFB;
    const ushort_t* dFl = dFlg + (size_t)b * DFB;

    f32x4 acc[4][4];
    #pragma unroll
    for (int i = 0; i < 4; ++i)
        #pragma unroll
        for (int j = 0; j < 4; ++j) acc[i][j] = (f32x4)0.f;

    f16x8 bhA[4], blA[4], bhB[4], blB[4];
    load_desc(dFh, dFl, w, 0, lane, bhA, blA);
    load_desc(dFh, dFl, w, 1, lane, bhB, blB);
    knn_chunk(fH, fL, la, lg, 0, bhA, blA, acc);
    load_desc(dFh, dFl, w, 2, lane, bhA, blA);
    knn_chunk(fH, fL, la, lg, 32, bhB, blB, acc);
    load_desc(dFh, dFl, w, 3, lane, bhB, blB);
    knn_chunk(fH, fL, la, lg, 64, bhA, blA, acc);
    load_desc(dFh, dFl, w, 4, lane, bhA, blA);
    knn_chunk(fH, fL, la, lg, 96, bhB, blB, acc);
    load_desc(dFh, dFl, w, 5, lane, bhB, blB);
    knn_chunk(fH, fL, la, lg, 128, bhA, blA, acc);
    load_desc(dFh, dFl, w, 6, lane, bhA, blA);
    knn_chunk(fH, fL, la, lg, 160, bhB, blB, acc);
    load_desc(dFh, dFl, w, 7, lane, bhB, blB);
    knn_chunk(fH, fL, la, lg, 192, bhA, blA, acc);
    knn_chunk(fH, fL, la, lg, 224, bhB, blB, acc);

    // ---- epilogue: dist + per-k argmin ----
    float nBv[4][4];
    #pragma unroll
    for (int i = 0; i < 4; ++i) {
        f32x4 t4 = *(const f32x4*)&nBS[i * 16 + lg * 4];
        nBv[i][0] = t4[0]; nBv[i][1] = t4[1]; nBv[i][2] = t4[2]; nBv[i][3] = t4[3];
    }
    int n0 = tile * 64;
    #pragma unroll
    for (int j = 0; j < 4; ++j) {
        int kl = wbase + j * 16 + la;
        float nAv = nAS[kl];
        unsigned long long best = ~0ull;
        #pragma unroll
        for (int i = 0; i < 4; ++i)
            #pragma unroll
            for (int r = 0; r < 4; ++r) {
                int n = n0 + i * 16 + lg * 4 + r;
                float d = fmaf(-2.f, acc[i][j][r], nAv) + nBv[i][r];
                unsigned u = __float_as_uint(d);
                u = (u & 0x80000000u) ? ~u : (u | 0x80000000u);
                unsigned long long key = ((unsigned long long)u << 32) | (unsigned)n;
                best = u64min(best, key);
            }
        best = u64min(best, shfl_xor_u64(best, 16));
        best = u64min(best, shfl_xor_u64(best, 32));
        if (lg == 0)
            scratch[(size_t)(b * KK + kl) * 256 + tile] = best;
    }
}

// =====================================================================
// Final argmin reduce over the 256 tiles -> minN[b*KK + k]
// =====================================================================
__global__ __launch_bounds__(64) void reduce_kernel(
        const unsigned long long* __restrict__ scratch, int* __restrict__ minN)
{
    int bk = blockIdx.x;              // b*KK + k
    int t = threadIdx.x;
    const unsigned long long* s = scratch + (size_t)bk * 256;
    unsigned long long best = s[t];
    best = u64min(best, s[t + 64]);
    best = u64min(best, s[t + 128]);
    best = u64min(best, s[t + 192]);
    for (int off = 32; off > 0; off >>= 1)
        best = u64min(best, shfl_down_u64(best, off));
    if (t == 0) minN[bk] = (int)(best & 0xffffffffULL);
}

// =====================================================================
// Two tiny MLPs: x(256) -> 128 relu -> 1. block per (b, which), 128 threads.
// =====================================================================
__global__ __launch_bounds__(128) void mlp_kernel(
        const int* __restrict__ idxA, const int* __restrict__ minN,
        const float* __restrict__ W1r, const float* __restrict__ b1r,
        const float* __restrict__ W2r, const float* __restrict__ b2r,
        const float* __restrict__ W1c, const float* __restrict__ b1c,
        const float* __restrict__ W2c, const float* __restrict__ b2c,
        float* __restrict__ out)
{
    __shared__ float xS[KK];
    __shared__ float red[2];
    int blk = blockIdx.x;            // b*2 + which
    int b = blk >> 1, which = blk & 1;
    int t = threadIdx.x;             // 0..127

    for (int k = t; k < KK; k += 128) {
        int ia = idxA[b * KK + k];
        int nn = minN[b * KK + k];
        int rowA = ia >> 7, colA = ia & 127;
        int rowB = nn >> 7, colB = nn & 127;
        xS[k] = (which == 0) ? (float)(rowB - rowA) : (float)(colA - colB);
    }
    __syncthreads();

    const float* W1 = which ? W1c : W1r;
    const float* b1 = which ? b1c : b1r;
    const float* W2 = which ? W2c : W2r;
    const float* b2 = which ? b2c : b2r;

    float h = b1[t];
    for (int k = 0; k < KK; ++k) h = fmaf(xS[k], W1[k * HID + t], h);
    h = fmaxf(h, 0.f);
    float pv = h * W2[t];
    for (int off = 32; off > 0; off >>= 1) pv += __shfl_down(pv, off, 64);
    if ((t & 63) == 0) red[t >> 6] = pv;
    __syncthreads();
    if (t == 0) out[b * 2 + which] = red[0] + red[1] + b2[0];
}

// =====================================================================
extern "C" void kernel_launch(void* const* d_in, const int* in_sizes, int n_in,
                              void* d_out, int out_size, void* d_ws, size_t ws_size,
                              hipStream_t stream)
{
    const float* xA  = (const float*)d_in[0];
    const float* xB  = (const float*)d_in[1];
    const float* Wc  = (const float*)d_in[2];
    const float* bc  = (const float*)d_in[3];
    const float* W1r = (const float*)d_in[4];
    const float* b1r = (const float*)d_in[5];
    const float* W2r = (const float*)d_in[6];
    const float* b2r = (const float*)d_in[7];
    const float* W1c = (const float*)d_in[8];
    const float* b1c = (const float*)d_in[9];
    const float* W2c = (const float*)d_in[10];
    const float* b2c = (const float*)d_in[11];
    float* out = (float*)d_out;

    char* ws = (char*)d_ws;
    unsigned long long* scratch = (unsigned long long*)ws; ws += (size_t)NB * KK * 256 * 8;
    int*   idxA   = (int*)ws;      ws += (size_t)NB * KK * 4;
    int*   minN   = (int*)ws;      ws += (size_t)NB * KK * 4;
    float* normA  = (float*)ws;    ws += (size_t)NB * KK * 4;
    float* resp   = (float*)ws;    ws += (size_t)NB * NF * 4;
    ushort_t* dFh = (ushort_t*)ws; ws += (size_t)NB * DFB * 2;
    ushort_t* dFl = (ushort_t*)ws; ws += (size_t)NB * DFB * 2;
    ushort_t* WFh = (ushort_t*)ws; ws += (size_t)COUT * 32 * 2;
    ushort_t* WFl = (ushort_t*)ws; ws += (size_t)COUT * 32 * 2;

    prep_kernel  <<<1, 256, 0, stream>>>(Wc, WFh, WFl);
    convA_kernel <<<dim3(256, NB), 256, 0, stream>>>(xA, WFh, WFl, bc, resp);
    select_kernel<<<NB * KK, 256, 0, stream>>>(resp, xA, Wc, bc, idxA, dFh, dFl, normA);
    fused_kernel <<<dim3(256, NB), 256, 0, stream>>>(xB, WFh, WFl, bc, dFh, dFl,
                                                     normA, scratch);
    reduce_kernel<<<NB * KK, 64, 0, stream>>>(scratch, minN);
    mlp_kernel   <<<8, 128, 0, stream>>>(idxA, minN,
                                         W1r, b1r, W2r, b2r,
                                         W1c, b1c, W2c, b2c, out);
}